// Round 5
// baseline (13396.637 us; speedup 1.0000x reference)
//
#include <hip/hip_runtime.h>
#include <hip/hip_bf16.h>

#define BB 32
#define TT 1024
#define EE 256
#define HH 512
#define H3 1536
#define MM (BB*TT)
#define NWG 16
#define EPS_BN 1e-3f

typedef __attribute__((ext_vector_type(8))) short bf16x8;
typedef __attribute__((ext_vector_type(4))) float f32x4;

__device__ __forceinline__ unsigned short f2bf(float f){
  unsigned u = __float_as_uint(f);
  u += 0x7fffu + ((u>>16)&1u);
  return (unsigned short)(u>>16);
}
__device__ __forceinline__ float bf2f(unsigned short u){
  return __uint_as_float(((unsigned)u)<<16);
}
// coherent (L3-point) ops — bypass non-coherent L1/L2
__device__ __forceinline__ uint4 ld16_coh(const void* p){
  uint4 r;
  asm volatile("global_load_dwordx4 %0, %1, off sc0 sc1" : "=v"(r) : "v"(p) : "memory");
  return r;
}
__device__ __forceinline__ void st8_coh(void* p, uint2 v){
  asm volatile("global_store_dwordx2 %0, %1, off sc0 sc1" :: "v"(p), "v"(v) : "memory");
}

// ---------- fp32 [K,N] -> bf16 [N,K] transpose ----------
__global__ __launch_bounds__(256) void conv_transpose(
    const float* __restrict__ in, unsigned short* __restrict__ out, int K, int N){
  __shared__ float tile[32][33];
  int k0 = blockIdx.x*32, n0 = blockIdx.y*32;
  int tx = threadIdx.x & 31, ty = threadIdx.x >> 5;
  for(int i=ty;i<32;i+=8) tile[i][tx] = in[(size_t)(k0+i)*N + n0 + tx];
  __syncthreads();
  for(int i=ty;i<32;i+=8) out[(size_t)(n0+i)*K + k0 + tx] = f2bf(tile[tx][i]);
}

// ---------- embedding gather -> bf16, t-major [T][B][E] ----------
__global__ __launch_bounds__(256) void gather_emb(
    const int* __restrict__ x, const float* __restrict__ emb,
    unsigned short* __restrict__ y0){
  int i = blockIdx.x*256 + threadIdx.x;
  if(i >= MM*EE/4) return;
  int row = i >> 6;                 // row = t*BB + b
  int c4 = (i & 63) << 2;
  int t = row >> 5, b = row & 31;
  float4 v = *(const float4*)&emb[(size_t)x[b*TT + t]*EE + c4];
  ushort4 o; o.x=f2bf(v.x); o.y=f2bf(v.y); o.z=f2bf(v.z); o.w=f2bf(v.w);
  *(ushort4*)&y0[(size_t)row*EE + c4] = o;
}

// ---------- C[M,N] = A[M,K](bf16) @ BT[N,K](bf16)^T + bias, fp32 out ----------
__global__ __launch_bounds__(256) void gemm_bias(
    const unsigned short* __restrict__ A,
    const unsigned short* __restrict__ BT,
    const float* __restrict__ bias,
    float* __restrict__ C, int Mdim, int Ndim, int Kdim){
  __shared__ __align__(16) unsigned short sA[64][72];
  __shared__ __align__(16) unsigned short sB[64][72];
  int m0 = blockIdx.x*64, n0 = blockIdx.y*64;
  int tid = threadIdx.x, ln = tid & 63, wv = tid >> 6;
  int wm = wv >> 1, wn = wv & 1;
  f32x4 acc[2][2] = {};
  for(int k0=0;k0<Kdim;k0+=64){
    __syncthreads();
    for(int p2=0;p2<2;p2++){
      int idx = (p2*256 + tid)*8;
      int r = idx >> 6, c = idx & 63;
      *(uint4*)&sA[r][c] = *(const uint4*)&A[(size_t)(m0+r)*Kdim + k0 + c];
      *(uint4*)&sB[r][c] = *(const uint4*)&BT[(size_t)(n0+r)*Kdim + k0 + c];
    }
    __syncthreads();
    for(int kk=0;kk<64;kk+=32){
      int kf = kk + ((ln>>4)<<3);
      bf16x8 af[2], bfr[2];
      for(int i=0;i<2;i++){
        af[i]  = *(const bf16x8*)&sA[wm*32 + i*16 + (ln&15)][kf];
        bfr[i] = *(const bf16x8*)&sB[wn*32 + i*16 + (ln&15)][kf];
      }
      for(int mi=0;mi<2;mi++)
        for(int ni=0;ni<2;ni++)
          acc[mi][ni] = __builtin_amdgcn_mfma_f32_16x16x32_bf16(af[mi], bfr[ni], acc[mi][ni], 0,0,0);
    }
  }
  for(int mi=0;mi<2;mi++)
    for(int ni=0;ni<2;ni++){
      int gn = n0 + wn*32 + ni*16 + (ln&15);
      float bs = bias ? bias[gn] : 0.f;
      int gm0 = m0 + wm*32 + mi*16 + ((ln>>4)<<2);
      for(int r2=0;r2<4;r2++)
        C[(size_t)(gm0+r2)*Ndim + gn] = acc[mi][ni][r2] + bs;
    }
}

// ---------- persistent GRU scan: 16 WGs, weights in VGPRs, no LDS in loop ----
// D[ch][b] = mfma(W_frag(A), H_frag(B)). Each thread: 4 consecutive channels
// x 1 batch element. Cross-WG h exchange via sc0/sc1 coherent 16B loads /
// 8B stores. Hbuf layout: [2 parity][B][512] bf16.
__global__ __launch_bounds__(256,1) void gru_scan(
    const float* __restrict__ xproj,        // [C][B][3H] fp32
    const unsigned short* __restrict__ rkT, // [1536][512] bf16
    const float* __restrict__ br,           // [1536]
    float* __restrict__ hstate,             // [B][512] fp32, in/out
    unsigned short* __restrict__ ybf,       // [C][B][512] bf16 (pre-offset)
    float* __restrict__ stats,              // [2][512] accumulated
    unsigned short* Hbuf,                   // [2][B][512] bf16 ping-pong
    int* flags, int C, int wbase){
  __shared__ float sredA[4][16];
  __shared__ float sredQ[4][16];
  const int wg = blockIdx.x, c0 = wg*32;
  const int tid = threadIdx.x, ln = tid & 63, wv = tid >> 6;
  const int wch = wv >> 1, wb = wv & 1;   // channel half / batch half
  const int q = ln >> 4;                  // quad 0..3
  const int frow = ln & 15;               // fragment row
  const int b = wb*16 + frow;             // this thread's batch element
  const int chb = c0 + wch*16 + (q<<2);   // first of this thread's 4 channels
  const int kofs = q << 3;                // k offset within 32-wide K step

  // persistent weight A-fragments: wf[g][kk] (192 VGPRs)
  bf16x8 wf[3][16];
  #pragma unroll
  for(int g=0; g<3; g++){
    const unsigned short* wsrc = &rkT[(size_t)(g*HH + c0 + wch*16 + frow)*HH];
    #pragma unroll
    for(int kk=0; kk<16; kk++)
      wf[g][kk] = *(const bf16x8*)&wsrc[kk*32 + kofs];
  }
  const f32x4 brz4 = *(const f32x4*)&br[0*HH + chb];
  const f32x4 brr4 = *(const f32x4*)&br[1*HH + chb];
  const f32x4 brh4 = *(const f32x4*)&br[2*HH + chb];

  // init h (4 channels x 1 batch) + publish into parity 0
  f32x4 hv = *(const f32x4*)&hstate[b*HH + chb];
  {
    uint2 o;
    o.x = ((unsigned)f2bf(hv[1])<<16) | f2bf(hv[0]);
    o.y = ((unsigned)f2bf(hv[3])<<16) | f2bf(hv[2]);
    st8_coh(&Hbuf[(size_t)b*HH + chb], o);
  }
  asm volatile("s_waitcnt vmcnt(0)" ::: "memory");
  __syncthreads();
  if(tid==0) __hip_atomic_store(&flags[wg], wbase+1, __ATOMIC_RELAXED, __HIP_MEMORY_SCOPE_AGENT);
  f32x4 as = {0,0,0,0}, aq = {0,0,0,0};

  for(int s=0; s<C; s++){
    const int par = s & 1;
    // xproj for step s — issued early, hides under poll
    const float* xp = &xproj[(size_t)s*BB*H3 + (size_t)b*H3];
    f32x4 xz4 = *(const f32x4*)&xp[chb];
    f32x4 xr4 = *(const f32x4*)&xp[HH + chb];
    f32x4 xh4 = *(const f32x4*)&xp[2*HH + chb];
    // wave 0 polls the 16 per-WG flags (relaxed, coherent)
    if(wv==0){
      const int need = wbase + s + 1;
      int guard = 0; bool done = false;
      while(!done && guard < 200000){
        int v = (ln < NWG) ? __hip_atomic_load(&flags[ln], __ATOMIC_RELAXED, __HIP_MEMORY_SCOPE_AGENT)
                           : 0x7fffffff;
        done = __all(v >= need) != 0;
        if(!done){ __builtin_amdgcn_s_sleep(1); guard++; }
      }
    }
    __syncthreads();
    // B-fragments: h(s) rows wb*16+frow, direct global->reg (coherent)
    const unsigned short* hsrc = &Hbuf[((size_t)par*BB + wb*16 + frow)*HH];
    uint4 hb[16];
    #pragma unroll
    for(int kk=0; kk<16; kk++)
      hb[kk] = ld16_coh(&hsrc[kk*32 + kofs]);
    asm volatile("s_waitcnt vmcnt(0)" ::: "memory");
    __builtin_amdgcn_sched_barrier(0);
    f32x4 acc[3] = {};
    #pragma unroll
    for(int kk=0; kk<16; kk++){
      union { uint4 u; bf16x8 v; } hf; hf.u = hb[kk];
      acc[0] = __builtin_amdgcn_mfma_f32_16x16x32_bf16(wf[0][kk], hf.v, acc[0], 0,0,0);
      acc[1] = __builtin_amdgcn_mfma_f32_16x16x32_bf16(wf[1][kk], hf.v, acc[1], 0,0,0);
      acc[2] = __builtin_amdgcn_mfma_f32_16x16x32_bf16(wf[2][kk], hf.v, acc[2], 0,0,0);
    }
    // gates (4 channels, this thread's batch element)
    #pragma unroll
    for(int r2=0;r2<4;r2++){
      float z  = 1.f/(1.f + __expf(-(xz4[r2] + acc[0][r2] + brz4[r2])));
      float rr = 1.f/(1.f + __expf(-(xr4[r2] + acc[1][r2] + brr4[r2])));
      float cd = fmaxf(xh4[r2] + rr*(acc[2][r2] + brh4[r2]), 0.f);
      float hn = z*hv[r2] + (1.f - z)*cd;
      hv[r2] = hn;
      as[r2] += hn; aq[r2] += hn*hn;
    }
    // publish h(s+1): one 8B coherent store
    uint2 o;
    o.x = ((unsigned)f2bf(hv[1])<<16) | f2bf(hv[0]);
    o.y = ((unsigned)f2bf(hv[3])<<16) | f2bf(hv[2]);
    st8_coh(&Hbuf[((size_t)(1-par)*BB + b)*HH + chb], o);
    asm volatile("s_waitcnt vmcnt(0)" ::: "memory");
    __syncthreads();
    if(tid==0) __hip_atomic_store(&flags[wg], wbase+s+2, __ATOMIC_RELAXED, __HIP_MEMORY_SCOPE_AGENT);
    // y store (plain, after flag — only needed at kernel end)
    *(uint2*)&ybf[((size_t)s*BB + b)*HH + chb] = o;
  }
  // final state
  *(f32x4*)&hstate[b*HH + chb] = hv;
  // BN stats: reduce over batch (lanes 0-15 within each quad-group)
  #pragma unroll
  for(int d=1; d<16; d<<=1){
    #pragma unroll
    for(int r2=0;r2<4;r2++){
      as[r2] += __shfl_xor(as[r2], d);
      aq[r2] += __shfl_xor(aq[r2], d);
    }
  }
  if(frow==0){
    #pragma unroll
    for(int r2=0;r2<4;r2++){
      sredA[wv][(q<<2)+r2] = as[r2];
      sredQ[wv][(q<<2)+r2] = aq[r2];
    }
  }
  __syncthreads();
  if(tid < 32){
    int i = tid & 15, wc = tid >> 4;
    stats[c0 + wc*16 + i]      += sredA[wc*2][i] + sredA[wc*2+1][i];
    stats[HH + c0 + wc*16 + i] += sredQ[wc*2][i] + sredQ[wc*2+1][i];
  }
}

// ---------- BN prep: stats -> scale/shift ----------
__global__ void bn_prep(const float* __restrict__ stats,
                        const float* __restrict__ gamma, const float* __restrict__ beta,
                        float* __restrict__ scsh){
  int c = blockIdx.x*256 + threadIdx.x;
  if(c >= HH) return;
  const float inv = 1.f/(float)MM;
  float mean = stats[c]*inv;
  float var  = stats[HH+c]*inv - mean*mean;
  float s = gamma[c]*rsqrtf(var + EPS_BN);
  scsh[c] = s; scsh[HH+c] = beta[c] - mean*s;
}

// ---------- fold BN into next GEMM ----------
__global__ __launch_bounds__(256) void kscale(
    const unsigned short* __restrict__ kT, const float* __restrict__ scsh,
    const float* __restrict__ bias, unsigned short* __restrict__ kTs,
    float* __restrict__ badj){
  int n = blockIdx.x*4 + (threadIdx.x >> 6);
  int ln = threadIdx.x & 63;
  int k = ln*8;
  uint4 v = *(const uint4*)&kT[(size_t)n*HH + k];
  unsigned short* pv = (unsigned short*)&v;
  unsigned short ov[8];
  float acc = 0.f;
  for(int j=0;j<8;j++){
    float f = bf2f(pv[j]);
    acc += scsh[HH + k + j] * f;
    ov[j] = f2bf(f * scsh[k + j]);
  }
  *(uint4*)&kTs[(size_t)n*HH + k] = *(uint4*)ov;
  for(int d=1; d<64; d<<=1) acc += __shfl_xor(acc, d);
  if(ln==0) badj[n] = bias[n] + acc;
}

// ---------- final BN + transpose to [B][T][H] fp32 ----------
__global__ __launch_bounds__(256) void final_out(
    const unsigned short* __restrict__ ybf, const float* __restrict__ scsh,
    float* __restrict__ out){
  int row = blockIdx.x*4 + (threadIdx.x >> 6);   // t*BB + b
  int ln = threadIdx.x & 63;
  int t = row >> 5, b = row & 31;
  int k = ln*8;
  uint4 v = *(const uint4*)&ybf[(size_t)row*HH + k];
  unsigned short* pv = (unsigned short*)&v;
  float o[8];
  for(int j=0;j<8;j++) o[j] = bf2f(pv[j])*scsh[k+j] + scsh[HH+k+j];
  float4* dst = (float4*)&out[((size_t)b*TT + t)*HH + k];
  dst[0] = make_float4(o[0],o[1],o[2],o[3]);
  dst[1] = make_float4(o[4],o[5],o[6],o[7]);
}

__global__ void copy_f32(const float* __restrict__ in, float* __restrict__ out, int n){
  int i = blockIdx.x*blockDim.x + threadIdx.x;
  if(i<n) out[i] = in[i];
}

extern "C" void kernel_launch(void* const* d_in, const int* in_sizes, int n_in,
                              void* d_out, int out_size, void* d_ws, size_t ws_size,
                              hipStream_t stream){
  const int*   x      = (const int*)d_in[0];
  const float* emb    = (const float*)d_in[1];
  const float* k0     = (const float*)d_in[2];
  const float* rk0    = (const float*)d_in[3];
  const float* b0     = (const float*)d_in[4];
  const float* krest  = (const float*)d_in[5];
  const float* rkrest = (const float*)d_in[6];
  const float* brest  = (const float*)d_in[7];
  const float* gammas = (const float*)d_in[8];
  const float* betas  = (const float*)d_in[9];
  float* out_y = (float*)d_out;
  float* out_state = out_y + (size_t)MM*HH;

  char* p = (char*)d_ws;
  auto alloc = [&](size_t bytes)->void*{ void* r = p; p += (bytes + 255) & ~(size_t)255; return r; };
  unsigned short* ybf  = (unsigned short*)alloc((size_t)MM*HH*2);   // [T][B][H]
  unsigned short* y0bf = (unsigned short*)alloc((size_t)MM*EE*2);   // [T][B][E]
  unsigned short* kT0  = (unsigned short*)alloc((size_t)H3*EE*2);
  unsigned short* kT1  = (unsigned short*)alloc((size_t)H3*HH*2);
  unsigned short* kT2  = (unsigned short*)alloc((size_t)H3*HH*2);
  unsigned short* rkT0 = (unsigned short*)alloc((size_t)H3*HH*2);
  unsigned short* rkT1 = (unsigned short*)alloc((size_t)H3*HH*2);
  unsigned short* rkT2 = (unsigned short*)alloc((size_t)H3*HH*2);
  unsigned short* kTs  = (unsigned short*)alloc((size_t)H3*HH*2);
  float* badj   = (float*)alloc(H3*4);
  float* scsh   = (float*)alloc(2*HH*4);
  float* stats  = (float*)alloc(2*HH*4);
  float* hstate = (float*)alloc((size_t)BB*HH*4);
  unsigned short* Hbuf = (unsigned short*)alloc((size_t)2*BB*HH*2);
  int* flags = (int*)alloc(NWG*4);
  size_t fixed_bytes = (size_t)(p - (char*)d_ws);

  int C = 64;
  const int cands[4] = {1024, 512, 256, 128};
  for(int i=0;i<4;i++){
    if(fixed_bytes + (size_t)cands[i]*BB*H3*4 <= ws_size){ C = cands[i]; break; }
  }
  float* xproj = (float*)alloc((size_t)C*BB*H3*4);   // [C][B][3H]
  const int NC = TT / C;

  hipMemsetAsync(flags, 0, NWG*4, stream);
  hipMemsetAsync(hstate, 0, (size_t)BB*HH*4, stream);

  conv_transpose<<<dim3(EE/32, H3/32), 256, 0, stream>>>(k0, kT0, EE, H3);
  conv_transpose<<<dim3(HH/32, H3/32), 256, 0, stream>>>(krest, kT1, HH, H3);
  conv_transpose<<<dim3(HH/32, H3/32), 256, 0, stream>>>(krest + (size_t)HH*H3, kT2, HH, H3);
  conv_transpose<<<dim3(HH/32, H3/32), 256, 0, stream>>>(rk0, rkT0, HH, H3);
  conv_transpose<<<dim3(HH/32, H3/32), 256, 0, stream>>>(rkrest, rkT1, HH, H3);
  conv_transpose<<<dim3(HH/32, H3/32), 256, 0, stream>>>(rkrest + (size_t)HH*H3, rkT2, HH, H3);
  gather_emb<<<(MM*EE/4 + 255)/256, 256, 0, stream>>>(x, emb, y0bf);

  for(int L=0; L<3; L++){
    hipMemsetAsync(stats, 0, 2*HH*4, stream);
    const unsigned short* A; const unsigned short* BT; const float* bias;
    const unsigned short* rk; const float* rbias; int Kd;
    if(L == 0){
      A = y0bf; BT = kT0; bias = b0; rk = rkT0; rbias = b0 + H3; Kd = EE;
    } else {
      const unsigned short* kTn = (L==1) ? kT1 : kT2;
      const float* bn_bias = (L==1) ? brest : brest + 2*H3;
      kscale<<<H3/4, 256, 0, stream>>>(kTn, scsh, bn_bias, kTs, badj);
      A = ybf; BT = kTs; bias = badj; Kd = HH;
      rk = (L==1) ? rkT1 : rkT2;
      rbias = (L==1) ? brest + H3 : brest + 3*H3;
    }
    for(int c=0;c<NC;c++){
      int t0 = c*C;
      gemm_bias<<<dim3(C*BB/64, H3/64), 256, 0, stream>>>(
          A + (size_t)t0*BB*Kd, BT, bias, xproj, C*BB, H3, Kd);
      gru_scan<<<NWG, 256, 0, stream>>>(
          xproj, rk, rbias, hstate, ybf + (size_t)t0*BB*HH,
          stats, Hbuf, flags, C, L*(TT+1) + t0);
    }
    bn_prep<<<2, 256, 0, stream>>>(stats, gammas + L*HH, betas + L*HH, scsh);
  }
  final_out<<<MM/4, 256, 0, stream>>>(ybf, scsh, out_y);
  copy_f32<<<64, 256, 0, stream>>>(hstate, out_state, BB*HH);
}

// Round 7
// 10216.309 us; speedup vs baseline: 1.3113x; 1.3113x over previous
//
#include <hip/hip_runtime.h>
#include <hip/hip_bf16.h>

#define BB 32
#define TT 1024
#define EE 256
#define HH 512
#define H3 1536
#define MM (BB*TT)
#define NWG 16
#define EPS_BN 1e-3f

typedef __attribute__((ext_vector_type(8))) short bf16x8;
typedef __attribute__((ext_vector_type(4))) float f32x4;

__device__ __forceinline__ unsigned short f2bf(float f){
  unsigned u = __float_as_uint(f);
  u += 0x7fffu + ((u>>16)&1u);
  return (unsigned short)(u>>16);
}
__device__ __forceinline__ float bf2f(unsigned short u){
  return __uint_as_float(((unsigned)u)<<16);
}
// system-scope coherent (L3-point) ops — proven R4/R5 path
__device__ __forceinline__ uint4 ld16_coh(const void* p){
  uint4 r;
  asm volatile("global_load_dwordx4 %0, %1, off sc0 sc1" : "=v"(r) : "v"(p) : "memory");
  return r;
}
__device__ __forceinline__ void st8_coh(void* p, uint2 v){
  asm volatile("global_store_dwordx2 %0, %1, off sc0 sc1" :: "v"(p), "v"(v) : "memory");
}

// ---------- fp32 [K,N] -> bf16 [N,K] transpose ----------
__global__ __launch_bounds__(256) void conv_transpose(
    const float* __restrict__ in, unsigned short* __restrict__ out, int K, int N){
  __shared__ float tile[32][33];
  int k0 = blockIdx.x*32, n0 = blockIdx.y*32;
  int tx = threadIdx.x & 31, ty = threadIdx.x >> 5;
  for(int i=ty;i<32;i+=8) tile[i][tx] = in[(size_t)(k0+i)*N + n0 + tx];
  __syncthreads();
  for(int i=ty;i<32;i+=8) out[(size_t)(n0+i)*K + k0 + tx] = f2bf(tile[tx][i]);
}

// ---------- embedding gather -> bf16, t-major [T][B][E] ----------
__global__ __launch_bounds__(256) void gather_emb(
    const int* __restrict__ x, const float* __restrict__ emb,
    unsigned short* __restrict__ y0){
  int i = blockIdx.x*256 + threadIdx.x;
  if(i >= MM*EE/4) return;
  int row = i >> 6;                 // row = t*BB + b
  int c4 = (i & 63) << 2;
  int t = row >> 5, b = row & 31;
  float4 v = *(const float4*)&emb[(size_t)x[b*TT + t]*EE + c4];
  ushort4 o; o.x=f2bf(v.x); o.y=f2bf(v.y); o.z=f2bf(v.z); o.w=f2bf(v.w);
  *(ushort4*)&y0[(size_t)row*EE + c4] = o;
}

// ---------- C[M,N] = A[M,K](bf16) @ BT[N,K](bf16)^T + bias, fp32 out ----------
__global__ __launch_bounds__(256) void gemm_bias(
    const unsigned short* __restrict__ A,
    const unsigned short* __restrict__ BT,
    const float* __restrict__ bias,
    float* __restrict__ C, int Mdim, int Ndim, int Kdim){
  __shared__ __align__(16) unsigned short sA[64][72];
  __shared__ __align__(16) unsigned short sB[64][72];
  int m0 = blockIdx.x*64, n0 = blockIdx.y*64;
  int tid = threadIdx.x, ln = tid & 63, wv = tid >> 6;
  int wm = wv >> 1, wn = wv & 1;
  f32x4 acc[2][2] = {};
  for(int k0=0;k0<Kdim;k0+=64){
    __syncthreads();
    for(int p2=0;p2<2;p2++){
      int idx = (p2*256 + tid)*8;
      int r = idx >> 6, c = idx & 63;
      *(uint4*)&sA[r][c] = *(const uint4*)&A[(size_t)(m0+r)*Kdim + k0 + c];
      *(uint4*)&sB[r][c] = *(const uint4*)&BT[(size_t)(n0+r)*Kdim + k0 + c];
    }
    __syncthreads();
    for(int kk=0;kk<64;kk+=32){
      int kf = kk + ((ln>>4)<<3);
      bf16x8 af[2], bfr[2];
      for(int i=0;i<2;i++){
        af[i]  = *(const bf16x8*)&sA[wm*32 + i*16 + (ln&15)][kf];
        bfr[i] = *(const bf16x8*)&sB[wn*32 + i*16 + (ln&15)][kf];
      }
      for(int mi=0;mi<2;mi++)
        for(int ni=0;ni<2;ni++)
          acc[mi][ni] = __builtin_amdgcn_mfma_f32_16x16x32_bf16(af[mi], bfr[ni], acc[mi][ni], 0,0,0);
    }
  }
  for(int mi=0;mi<2;mi++)
    for(int ni=0;ni<2;ni++){
      int gn = n0 + wn*32 + ni*16 + (ln&15);
      float bs = bias ? bias[gn] : 0.f;
      int gm0 = m0 + wm*32 + mi*16 + ((ln>>4)<<2);
      for(int r2=0;r2<4;r2++)
        C[(size_t)(gm0+r2)*Ndim + gn] = acc[mi][ni][r2] + bs;
    }
}

// ---------- persistent GRU scan: 16 WGs; VGPR/L2 weights + LDS h-stage ------
// D[ch][b] = mfma(W_frag(A), H_frag(B)). Thread = 4 consecutive channels x 1
// batch element. Cross-WG exchange: sc0sc1 coherent 16B loads / 8B stores.
// Flags: one per WG, spread one cache line apart, relaxed agent atomics.
// Hbuf layout: [2 parity][B][512] bf16.
__global__ __launch_bounds__(256,1) void gru_scan(
    const float* __restrict__ xproj,        // [C][B][3H] fp32
    const unsigned short* __restrict__ rkT, // [1536][512] bf16
    const float* __restrict__ br,           // [1536]
    float* __restrict__ hstate,             // [B][512] fp32, in/out
    unsigned short* __restrict__ ybf,       // [C][B][512] bf16 (pre-offset)
    float* __restrict__ stats,              // [2][512] accumulated
    unsigned short* Hbuf,                   // [2][B][512] bf16 ping-pong
    int* flags, int C, int wbase){
  __shared__ __align__(16) unsigned short hlds[32][520];  // padded: stride 260dw
  __shared__ float sredA[4][16];
  __shared__ float sredQ[4][16];
  const int wg = blockIdx.x, c0 = wg*32;
  const int tid = threadIdx.x, ln = tid & 63, wv = tid >> 6;
  const int wch = wv >> 1, wb = wv & 1;   // channel half / batch half
  const int q = ln >> 4;                  // quad 0..3
  const int frow = ln & 15;               // fragment row
  const int b = wb*16 + frow;             // this thread's batch element
  const int chb = c0 + wch*16 + (q<<2);   // first of this thread's 4 channels
  const int kofs = q << 3;                // k offset within 32-wide K step

  // persistent weight A-fragments
  bf16x8 wf[3][16];
  #pragma unroll
  for(int g=0; g<3; g++){
    const unsigned short* wsrc = &rkT[(size_t)(g*HH + c0 + wch*16 + frow)*HH];
    #pragma unroll
    for(int kk=0; kk<16; kk++)
      wf[g][kk] = *(const bf16x8*)&wsrc[kk*32 + kofs];
  }
  const f32x4 brz4 = *(const f32x4*)&br[0*HH + chb];
  const f32x4 brr4 = *(const f32x4*)&br[1*HH + chb];
  const f32x4 brh4 = *(const f32x4*)&br[2*HH + chb];

  // init h + publish into parity 0
  f32x4 hv = *(const f32x4*)&hstate[b*HH + chb];
  {
    uint2 o;
    o.x = ((unsigned)f2bf(hv[1])<<16) | f2bf(hv[0]);
    o.y = ((unsigned)f2bf(hv[3])<<16) | f2bf(hv[2]);
    st8_coh(&Hbuf[(size_t)b*HH + chb], o);
  }
  asm volatile("s_waitcnt vmcnt(0)" ::: "memory");
  __syncthreads();
  if(tid==0) __hip_atomic_store(&flags[wg*16], wbase+1, __ATOMIC_RELAXED, __HIP_MEMORY_SCOPE_AGENT);
  f32x4 as = {0,0,0,0}, aq = {0,0,0,0};

  for(int s=0; s<C; s++){
    const int par = s & 1;
    // xproj for step s — issued early, completes during the poll
    const float* xp = &xproj[(size_t)s*BB*H3 + (size_t)b*H3];
    f32x4 xz4 = *(const f32x4*)&xp[chb];
    f32x4 xr4 = *(const f32x4*)&xp[HH + chb];
    f32x4 xh4 = *(const f32x4*)&xp[2*HH + chb];
    // wave 0 polls the 16 per-WG flags (one line each; no sleep)
    if(wv==0){
      const int need = wbase + s + 1;
      int guard = 0; bool done = false;
      while(!done && guard < 5000){
        int v = (ln < NWG) ? __hip_atomic_load(&flags[ln*16], __ATOMIC_RELAXED, __HIP_MEMORY_SCOPE_AGENT)
                           : 0x7fffffff;
        done = __all(v >= need) != 0;
        guard++;
      }
    }
    __syncthreads();
    // stage h(s): one contiguous 32KB sweep, coherent 16B loads -> LDS
    {
      const unsigned short* src = &Hbuf[(size_t)par*BB*HH];
      uint4 hb[8];
      #pragma unroll
      for(int j=0;j<8;j++) hb[j] = ld16_coh(&src[(j*256 + tid)*8]);
      asm volatile("s_waitcnt vmcnt(0)" ::: "memory");
      #pragma unroll
      for(int j=0;j<8;j++){
        int i = (j*256 + tid)*8;
        *(uint4*)&hlds[i>>9][i&511] = hb[j];
      }
    }
    __syncthreads();
    // inner products from LDS B-fragments
    f32x4 acc[3] = {};
    #pragma unroll
    for(int kk=0; kk<16; kk++){
      bf16x8 hf = *(const bf16x8*)&hlds[b][kk*32 + kofs];
      acc[0] = __builtin_amdgcn_mfma_f32_16x16x32_bf16(wf[0][kk], hf, acc[0], 0,0,0);
      acc[1] = __builtin_amdgcn_mfma_f32_16x16x32_bf16(wf[1][kk], hf, acc[1], 0,0,0);
      acc[2] = __builtin_amdgcn_mfma_f32_16x16x32_bf16(wf[2][kk], hf, acc[2], 0,0,0);
    }
    // gates
    #pragma unroll
    for(int r2=0;r2<4;r2++){
      float z  = 1.f/(1.f + __expf(-(xz4[r2] + acc[0][r2] + brz4[r2])));
      float rr = 1.f/(1.f + __expf(-(xr4[r2] + acc[1][r2] + brr4[r2])));
      float cd = fmaxf(xh4[r2] + rr*(acc[2][r2] + brh4[r2]), 0.f);
      float hn = z*hv[r2] + (1.f - z)*cd;
      hv[r2] = hn;
      as[r2] += hn; aq[r2] += hn*hn;
    }
    // publish h(s+1): one 8B coherent store, drain, sync, flag
    uint2 o;
    o.x = ((unsigned)f2bf(hv[1])<<16) | f2bf(hv[0]);
    o.y = ((unsigned)f2bf(hv[3])<<16) | f2bf(hv[2]);
    st8_coh(&Hbuf[((size_t)(1-par)*BB + b)*HH + chb], o);
    asm volatile("s_waitcnt vmcnt(0)" ::: "memory");
    __syncthreads();
    if(tid==0) __hip_atomic_store(&flags[wg*16], wbase+s+2, __ATOMIC_RELAXED, __HIP_MEMORY_SCOPE_AGENT);
    // y store (plain, off the critical path)
    *(uint2*)&ybf[((size_t)s*BB + b)*HH + chb] = o;
  }
  // final state
  *(f32x4*)&hstate[b*HH + chb] = hv;
  // BN stats: reduce over batch (16 lanes per quad-group)
  #pragma unroll
  for(int d=1; d<16; d<<=1){
    #pragma unroll
    for(int r2=0;r2<4;r2++){
      as[r2] += __shfl_xor(as[r2], d);
      aq[r2] += __shfl_xor(aq[r2], d);
    }
  }
  if(frow==0){
    #pragma unroll
    for(int r2=0;r2<4;r2++){
      sredA[wv][(q<<2)+r2] = as[r2];
      sredQ[wv][(q<<2)+r2] = aq[r2];
    }
  }
  __syncthreads();
  if(tid < 32){
    int i = tid & 15, wc = tid >> 4;
    stats[c0 + wc*16 + i]      += sredA[wc*2][i] + sredA[wc*2+1][i];
    stats[HH + c0 + wc*16 + i] += sredQ[wc*2][i] + sredQ[wc*2+1][i];
  }
}

// ---------- BN prep: stats -> scale/shift ----------
__global__ void bn_prep(const float* __restrict__ stats,
                        const float* __restrict__ gamma, const float* __restrict__ beta,
                        float* __restrict__ scsh){
  int c = blockIdx.x*256 + threadIdx.x;
  if(c >= HH) return;
  const float inv = 1.f/(float)MM;
  float mean = stats[c]*inv;
  float var  = stats[HH+c]*inv - mean*mean;
  float s = gamma[c]*rsqrtf(var + EPS_BN);
  scsh[c] = s; scsh[HH+c] = beta[c] - mean*s;
}

// ---------- fold BN into next GEMM ----------
__global__ __launch_bounds__(256) void kscale(
    const unsigned short* __restrict__ kT, const float* __restrict__ scsh,
    const float* __restrict__ bias, unsigned short* __restrict__ kTs,
    float* __restrict__ badj){
  int n = blockIdx.x*4 + (threadIdx.x >> 6);
  int ln = threadIdx.x & 63;
  int k = ln*8;
  uint4 v = *(const uint4*)&kT[(size_t)n*HH + k];
  unsigned short* pv = (unsigned short*)&v;
  unsigned short ov[8];
  float acc = 0.f;
  for(int j=0;j<8;j++){
    float f = bf2f(pv[j]);
    acc += scsh[HH + k + j] * f;
    ov[j] = f2bf(f * scsh[k + j]);
  }
  *(uint4*)&kTs[(size_t)n*HH + k] = *(uint4*)ov;
  for(int d=1; d<64; d<<=1) acc += __shfl_xor(acc, d);
  if(ln==0) badj[n] = bias[n] + acc;
}

// ---------- final BN + transpose to [B][T][H] fp32 ----------
__global__ __launch_bounds__(256) void final_out(
    const unsigned short* __restrict__ ybf, const float* __restrict__ scsh,
    float* __restrict__ out){
  int row = blockIdx.x*4 + (threadIdx.x >> 6);   // t*BB + b
  int ln = threadIdx.x & 63;
  int t = row >> 5, b = row & 31;
  int k = ln*8;
  uint4 v = *(const uint4*)&ybf[(size_t)row*HH + k];
  unsigned short* pv = (unsigned short*)&v;
  float o[8];
  for(int j=0;j<8;j++) o[j] = bf2f(pv[j])*scsh[k+j] + scsh[HH+k+j];
  float4* dst = (float4*)&out[((size_t)b*TT + t)*HH + k];
  dst[0] = make_float4(o[0],o[1],o[2],o[3]);
  dst[1] = make_float4(o[4],o[5],o[6],o[7]);
}

__global__ void copy_f32(const float* __restrict__ in, float* __restrict__ out, int n){
  int i = blockIdx.x*blockDim.x + threadIdx.x;
  if(i<n) out[i] = in[i];
}

extern "C" void kernel_launch(void* const* d_in, const int* in_sizes, int n_in,
                              void* d_out, int out_size, void* d_ws, size_t ws_size,
                              hipStream_t stream){
  const int*   x      = (const int*)d_in[0];
  const float* emb    = (const float*)d_in[1];
  const float* k0     = (const float*)d_in[2];
  const float* rk0    = (const float*)d_in[3];
  const float* b0     = (const float*)d_in[4];
  const float* krest  = (const float*)d_in[5];
  const float* rkrest = (const float*)d_in[6];
  const float* brest  = (const float*)d_in[7];
  const float* gammas = (const float*)d_in[8];
  const float* betas  = (const float*)d_in[9];
  float* out_y = (float*)d_out;
  float* out_state = out_y + (size_t)MM*HH;

  char* p = (char*)d_ws;
  auto alloc = [&](size_t bytes)->void*{ void* r = p; p += (bytes + 255) & ~(size_t)255; return r; };
  unsigned short* ybf  = (unsigned short*)alloc((size_t)MM*HH*2);   // [T][B][H]
  unsigned short* y0bf = (unsigned short*)alloc((size_t)MM*EE*2);   // [T][B][E]
  unsigned short* kT0  = (unsigned short*)alloc((size_t)H3*EE*2);
  unsigned short* kT1  = (unsigned short*)alloc((size_t)H3*HH*2);
  unsigned short* kT2  = (unsigned short*)alloc((size_t)H3*HH*2);
  unsigned short* rkT0 = (unsigned short*)alloc((size_t)H3*HH*2);
  unsigned short* rkT1 = (unsigned short*)alloc((size_t)H3*HH*2);
  unsigned short* rkT2 = (unsigned short*)alloc((size_t)H3*HH*2);
  unsigned short* kTs  = (unsigned short*)alloc((size_t)H3*HH*2);
  float* badj   = (float*)alloc(H3*4);
  float* scsh   = (float*)alloc(2*HH*4);
  float* stats  = (float*)alloc(2*HH*4);
  float* hstate = (float*)alloc((size_t)BB*HH*4);
  unsigned short* Hbuf = (unsigned short*)alloc((size_t)2*BB*HH*2);
  int* flags = (int*)alloc(NWG*16*4);   // one cache line per WG
  size_t fixed_bytes = (size_t)(p - (char*)d_ws);

  int C = 64;
  const int cands[4] = {1024, 512, 256, 128};
  for(int i=0;i<4;i++){
    if(fixed_bytes + (size_t)cands[i]*BB*H3*4 <= ws_size){ C = cands[i]; break; }
  }
  float* xproj = (float*)alloc((size_t)C*BB*H3*4);   // [C][B][3H]
  const int NC = TT / C;

  hipMemsetAsync(flags, 0, NWG*16*4, stream);
  hipMemsetAsync(hstate, 0, (size_t)BB*HH*4, stream);

  conv_transpose<<<dim3(EE/32, H3/32), 256, 0, stream>>>(k0, kT0, EE, H3);
  conv_transpose<<<dim3(HH/32, H3/32), 256, 0, stream>>>(krest, kT1, HH, H3);
  conv_transpose<<<dim3(HH/32, H3/32), 256, 0, stream>>>(krest + (size_t)HH*H3, kT2, HH, H3);
  conv_transpose<<<dim3(HH/32, H3/32), 256, 0, stream>>>(rk0, rkT0, HH, H3);
  conv_transpose<<<dim3(HH/32, H3/32), 256, 0, stream>>>(rkrest, rkT1, HH, H3);
  conv_transpose<<<dim3(HH/32, H3/32), 256, 0, stream>>>(rkrest + (size_t)HH*H3, rkT2, HH, H3);
  gather_emb<<<(MM*EE/4 + 255)/256, 256, 0, stream>>>(x, emb, y0bf);

  for(int L=0; L<3; L++){
    hipMemsetAsync(stats, 0, 2*HH*4, stream);
    const unsigned short* A; const unsigned short* BT; const float* bias;
    const unsigned short* rk; const float* rbias; int Kd;
    if(L == 0){
      A = y0bf; BT = kT0; bias = b0; rk = rkT0; rbias = b0 + H3; Kd = EE;
    } else {
      const unsigned short* kTn = (L==1) ? kT1 : kT2;
      const float* bn_bias = (L==1) ? brest : brest + 2*H3;
      kscale<<<H3/4, 256, 0, stream>>>(kTn, scsh, bn_bias, kTs, badj);
      A = ybf; BT = kTs; bias = badj; Kd = HH;
      rk = (L==1) ? rkT1 : rkT2;
      rbias = (L==1) ? brest + H3 : brest + 3*H3;
    }
    for(int c=0;c<NC;c++){
      int t0 = c*C;
      gemm_bias<<<dim3(C*BB/64, H3/64), 256, 0, stream>>>(
          A + (size_t)t0*BB*Kd, BT, bias, xproj, C*BB, H3, Kd);
      gru_scan<<<NWG, 256, 0, stream>>>(
          xproj, rk, rbias, hstate, ybf + (size_t)t0*BB*HH,
          stats, Hbuf, flags, C, L*(TT+1) + t0);
    }
    bn_prep<<<2, 256, 0, stream>>>(stats, gammas + L*HH, betas + L*HH, scsh);
  }
  final_out<<<MM/4, 256, 0, stream>>>(ybf, scsh, out_y);
  copy_f32<<<64, 256, 0, stream>>>(hstate, out_state, BB*HH);
}

// Round 8
// 9125.989 us; speedup vs baseline: 1.4680x; 1.1195x over previous
//
#include <hip/hip_runtime.h>
#include <hip/hip_bf16.h>

#define BB 32
#define TT 1024
#define EE 256
#define HH 512
#define H3 1536
#define MM (BB*TT)
#define NWG 16
#define EPS_BN 1e-3f

typedef __attribute__((ext_vector_type(8))) short bf16x8;
typedef __attribute__((ext_vector_type(4))) float f32x4;

__device__ __forceinline__ unsigned short f2bf(float f){
  unsigned u = __float_as_uint(f);
  u += 0x7fffu + ((u>>16)&1u);
  return (unsigned short)(u>>16);
}
__device__ __forceinline__ float bf2f(unsigned short u){
  return __uint_as_float(((unsigned)u)<<16);
}
// system-scope coherent (L3-point) ops — proven R4/R5/R7 path
__device__ __forceinline__ uint4 ld16_coh(const void* p){
  uint4 r;
  asm volatile("global_load_dwordx4 %0, %1, off sc0 sc1" : "=v"(r) : "v"(p) : "memory");
  return r;
}
__device__ __forceinline__ void st8_coh(void* p, uint2 v){
  asm volatile("global_store_dwordx2 %0, %1, off sc0 sc1" :: "v"(p), "v"(v) : "memory");
}

// ---------- fp32 [K,N] -> bf16 [N,K] transpose ----------
__global__ __launch_bounds__(256) void conv_transpose(
    const float* __restrict__ in, unsigned short* __restrict__ out, int K, int N){
  __shared__ float tile[32][33];
  int k0 = blockIdx.x*32, n0 = blockIdx.y*32;
  int tx = threadIdx.x & 31, ty = threadIdx.x >> 5;
  for(int i=ty;i<32;i+=8) tile[i][tx] = in[(size_t)(k0+i)*N + n0 + tx];
  __syncthreads();
  for(int i=ty;i<32;i+=8) out[(size_t)(n0+i)*K + k0 + tx] = f2bf(tile[tx][i]);
}

// ---------- embedding gather -> bf16, t-major [T][B][E] ----------
__global__ __launch_bounds__(256) void gather_emb(
    const int* __restrict__ x, const float* __restrict__ emb,
    unsigned short* __restrict__ y0){
  int i = blockIdx.x*256 + threadIdx.x;
  if(i >= MM*EE/4) return;
  int row = i >> 6;                 // row = t*BB + b
  int c4 = (i & 63) << 2;
  int t = row >> 5, b = row & 31;
  float4 v = *(const float4*)&emb[(size_t)x[b*TT + t]*EE + c4];
  ushort4 o; o.x=f2bf(v.x); o.y=f2bf(v.y); o.z=f2bf(v.z); o.w=f2bf(v.w);
  *(ushort4*)&y0[(size_t)row*EE + c4] = o;
}

// ---------- C[M,N] = A[M,K](bf16) @ BT[N,K](bf16)^T + bias, fp32 out ----------
__global__ __launch_bounds__(256) void gemm_bias(
    const unsigned short* __restrict__ A,
    const unsigned short* __restrict__ BT,
    const float* __restrict__ bias,
    float* __restrict__ C, int Mdim, int Ndim, int Kdim){
  __shared__ __align__(16) unsigned short sA[64][72];
  __shared__ __align__(16) unsigned short sB[64][72];
  int m0 = blockIdx.x*64, n0 = blockIdx.y*64;
  int tid = threadIdx.x, ln = tid & 63, wv = tid >> 6;
  int wm = wv >> 1, wn = wv & 1;
  f32x4 acc[2][2] = {};
  for(int k0=0;k0<Kdim;k0+=64){
    __syncthreads();
    for(int p2=0;p2<2;p2++){
      int idx = (p2*256 + tid)*8;
      int r = idx >> 6, c = idx & 63;
      *(uint4*)&sA[r][c] = *(const uint4*)&A[(size_t)(m0+r)*Kdim + k0 + c];
      *(uint4*)&sB[r][c] = *(const uint4*)&BT[(size_t)(n0+r)*Kdim + k0 + c];
    }
    __syncthreads();
    for(int kk=0;kk<64;kk+=32){
      int kf = kk + ((ln>>4)<<3);
      bf16x8 af[2], bfr[2];
      for(int i=0;i<2;i++){
        af[i]  = *(const bf16x8*)&sA[wm*32 + i*16 + (ln&15)][kf];
        bfr[i] = *(const bf16x8*)&sB[wn*32 + i*16 + (ln&15)][kf];
      }
      for(int mi=0;mi<2;mi++)
        for(int ni=0;ni<2;ni++)
          acc[mi][ni] = __builtin_amdgcn_mfma_f32_16x16x32_bf16(af[mi], bfr[ni], acc[mi][ni], 0,0,0);
    }
  }
  for(int mi=0;mi<2;mi++)
    for(int ni=0;ni<2;ni++){
      int gn = n0 + wn*32 + ni*16 + (ln&15);
      float bs = bias ? bias[gn] : 0.f;
      int gm0 = m0 + wm*32 + mi*16 + ((ln>>4)<<2);
      for(int r2=0;r2<4;r2++)
        C[(size_t)(gm0+r2)*Ndim + gn] = acc[mi][ni][r2] + bs;
    }
}

// ---------- persistent GRU scan: 2-D partition (8 ch-groups x 2 batch-groups)
// 16 WGs; WG(cg,bg) owns 64 channels x 16 batch rows. Batch rows are GRU-
// independent => two disjoint sync domains of 8 WGs (same bg). Per step a WG
// consumes h[its 16 rows][all 512 ch] = 16KB. Weights VGPR-resident.
// Cross-WG exchange: sc0sc1 coherent ops; flags one line/WG, relaxed agent.
// Hbuf: [2 parity][B][512] bf16. stats: [2 bg][2][512] exclusive halves.
__global__ __launch_bounds__(256,1) void gru_scan(
    const float* __restrict__ xproj,        // [C][B][3H] fp32
    const unsigned short* __restrict__ rkT, // [1536][512] bf16
    const float* __restrict__ br,           // [1536]
    float* __restrict__ hstate,             // [B][512] fp32, in/out
    unsigned short* __restrict__ ybf,       // [C][B][512] bf16 (pre-offset)
    float* __restrict__ stats,              // [2][2][512]
    unsigned short* Hbuf,                   // [2][B][512] bf16 ping-pong
    int* flags, int C, int wbase){
  __shared__ __align__(16) unsigned short hlds[16][520];  // 16 rows, padded
  __shared__ float sredA[4][16];
  __shared__ float sredQ[4][16];
  const int wg = blockIdx.x;
  const int cg = wg >> 1, bg = wg & 1;
  const int chbase = cg*64;
  const int tid = threadIdx.x, ln = tid & 63, wv = tid >> 6;
  const int q = ln >> 4, frow = ln & 15;
  const int b = bg*16 + frow;              // batch element (D col / gates)
  const int chb = chbase + wv*16 + (q<<2); // first of this thread's 4 channels
  const int wrow = chbase + wv*16 + frow;  // A-frag channel row
  const int kofs = q << 3;

  // persistent weight A-fragments: 16 ch per wave, 192 VGPRs
  bf16x8 wf[3][16];
  #pragma unroll
  for(int g=0; g<3; g++){
    const unsigned short* wsrc = &rkT[(size_t)(g*HH + wrow)*HH];
    #pragma unroll
    for(int kk=0; kk<16; kk++)
      wf[g][kk] = *(const bf16x8*)&wsrc[kk*32 + kofs];
  }
  const f32x4 brz4 = *(const f32x4*)&br[0*HH + chb];
  const f32x4 brr4 = *(const f32x4*)&br[1*HH + chb];
  const f32x4 brh4 = *(const f32x4*)&br[2*HH + chb];

  // init h + publish into parity 0
  f32x4 hv = *(const f32x4*)&hstate[b*HH + chb];
  {
    uint2 o;
    o.x = ((unsigned)f2bf(hv[1])<<16) | f2bf(hv[0]);
    o.y = ((unsigned)f2bf(hv[3])<<16) | f2bf(hv[2]);
    st8_coh(&Hbuf[(size_t)b*HH + chb], o);
  }
  asm volatile("s_waitcnt vmcnt(0)" ::: "memory");
  __syncthreads();
  if(tid==0) __hip_atomic_store(&flags[wg*16], wbase+1, __ATOMIC_RELAXED, __HIP_MEMORY_SCOPE_AGENT);
  f32x4 as = {0,0,0,0}, aq = {0,0,0,0};

  for(int s=0; s<C; s++){
    const int par = s & 1;
    // xproj for step s — issued early, completes during the poll
    const float* xp = &xproj[(size_t)s*BB*H3 + (size_t)b*H3];
    f32x4 xz4 = *(const f32x4*)&xp[chb];
    f32x4 xr4 = *(const f32x4*)&xp[HH + chb];
    f32x4 xh4 = *(const f32x4*)&xp[2*HH + chb];
    // wave 0 polls the 8 same-domain flags (one line each; no sleep)
    if(wv==0){
      const int need = wbase + s + 1;
      int guard = 0; bool done = false;
      while(!done && guard < 200000){
        int v = (ln < 8) ? __hip_atomic_load(&flags[(ln*2+bg)*16], __ATOMIC_RELAXED, __HIP_MEMORY_SCOPE_AGENT)
                         : 0x7fffffff;
        done = __all(v >= need) != 0;
        guard++;
      }
    }
    __syncthreads();
    // stage h(s) for own 16 batch rows: 16KB sweep, coherent 16B loads -> LDS
    {
      const unsigned short* src = &Hbuf[(size_t)par*BB*HH + (size_t)bg*16*HH];
      uint4 hb[4];
      #pragma unroll
      for(int j=0;j<4;j++) hb[j] = ld16_coh(&src[(j*256 + tid)*8]);
      asm volatile("s_waitcnt vmcnt(0)" ::: "memory");
      #pragma unroll
      for(int j=0;j<4;j++){
        int i = (j*256 + tid)*8;
        *(uint4*)&hlds[i>>9][i&511] = hb[j];
      }
    }
    __syncthreads();
    // inner products from LDS B-fragments (B col = frow)
    f32x4 acc[3] = {};
    #pragma unroll
    for(int kk=0; kk<16; kk++){
      bf16x8 hf = *(const bf16x8*)&hlds[frow][kk*32 + kofs];
      acc[0] = __builtin_amdgcn_mfma_f32_16x16x32_bf16(wf[0][kk], hf, acc[0], 0,0,0);
      acc[1] = __builtin_amdgcn_mfma_f32_16x16x32_bf16(wf[1][kk], hf, acc[1], 0,0,0);
      acc[2] = __builtin_amdgcn_mfma_f32_16x16x32_bf16(wf[2][kk], hf, acc[2], 0,0,0);
    }
    // gates (4 channels x this thread's batch element)
    #pragma unroll
    for(int r2=0;r2<4;r2++){
      float z  = 1.f/(1.f + __expf(-(xz4[r2] + acc[0][r2] + brz4[r2])));
      float rr = 1.f/(1.f + __expf(-(xr4[r2] + acc[1][r2] + brr4[r2])));
      float cd = fmaxf(xh4[r2] + rr*(acc[2][r2] + brh4[r2]), 0.f);
      float hn = z*hv[r2] + (1.f - z)*cd;
      hv[r2] = hn;
      as[r2] += hn; aq[r2] += hn*hn;
    }
    // publish h(s+1): one 8B coherent store, drain, sync, flag
    uint2 o;
    o.x = ((unsigned)f2bf(hv[1])<<16) | f2bf(hv[0]);
    o.y = ((unsigned)f2bf(hv[3])<<16) | f2bf(hv[2]);
    st8_coh(&Hbuf[((size_t)(1-par)*BB + b)*HH + chb], o);
    asm volatile("s_waitcnt vmcnt(0)" ::: "memory");
    __syncthreads();
    if(tid==0) __hip_atomic_store(&flags[wg*16], wbase+s+2, __ATOMIC_RELAXED, __HIP_MEMORY_SCOPE_AGENT);
    // y store (plain, off the critical path)
    *(uint2*)&ybf[((size_t)s*BB + b)*HH + chb] = o;
  }
  // final state
  *(f32x4*)&hstate[b*HH + chb] = hv;
  // BN stats: reduce over this domain's 16 batch rows (lanes frow 0..15)
  #pragma unroll
  for(int d=1; d<16; d<<=1){
    #pragma unroll
    for(int r2=0;r2<4;r2++){
      as[r2] += __shfl_xor(as[r2], d);
      aq[r2] += __shfl_xor(aq[r2], d);
    }
  }
  if(frow==0){
    #pragma unroll
    for(int r2=0;r2<4;r2++){
      sredA[wv][(q<<2)+r2] = as[r2];
      sredQ[wv][(q<<2)+r2] = aq[r2];
    }
  }
  __syncthreads();
  if(tid < 64){
    float* st = stats + (size_t)bg*2*HH;
    st[chbase + tid]      += sredA[tid>>4][tid&15];
    st[HH + chbase + tid] += sredQ[tid>>4][tid&15];
  }
}

// ---------- BN prep: stats (2 domain halves) -> scale/shift ----------
__global__ void bn_prep(const float* __restrict__ stats,
                        const float* __restrict__ gamma, const float* __restrict__ beta,
                        float* __restrict__ scsh){
  int c = blockIdx.x*256 + threadIdx.x;
  if(c >= HH) return;
  const float inv = 1.f/(float)MM;
  float s0 = stats[c] + stats[2*HH + c];
  float q0 = stats[HH + c] + stats[3*HH + c];
  float mean = s0*inv;
  float var  = q0*inv - mean*mean;
  float s = gamma[c]*rsqrtf(var + EPS_BN);
  scsh[c] = s; scsh[HH+c] = beta[c] - mean*s;
}

// ---------- fold BN into next GEMM ----------
__global__ __launch_bounds__(256) void kscale(
    const unsigned short* __restrict__ kT, const float* __restrict__ scsh,
    const float* __restrict__ bias, unsigned short* __restrict__ kTs,
    float* __restrict__ badj){
  int n = blockIdx.x*4 + (threadIdx.x >> 6);
  int ln = threadIdx.x & 63;
  int k = ln*8;
  uint4 v = *(const uint4*)&kT[(size_t)n*HH + k];
  unsigned short* pv = (unsigned short*)&v;
  unsigned short ov[8];
  float acc = 0.f;
  for(int j=0;j<8;j++){
    float f = bf2f(pv[j]);
    acc += scsh[HH + k + j] * f;
    ov[j] = f2bf(f * scsh[k + j]);
  }
  *(uint4*)&kTs[(size_t)n*HH + k] = *(uint4*)ov;
  for(int d=1; d<64; d<<=1) acc += __shfl_xor(acc, d);
  if(ln==0) badj[n] = bias[n] + acc;
}

// ---------- final BN + transpose to [B][T][H] fp32 ----------
__global__ __launch_bounds__(256) void final_out(
    const unsigned short* __restrict__ ybf, const float* __restrict__ scsh,
    float* __restrict__ out){
  int row = blockIdx.x*4 + (threadIdx.x >> 6);   // t*BB + b
  int ln = threadIdx.x & 63;
  int t = row >> 5, b = row & 31;
  int k = ln*8;
  uint4 v = *(const uint4*)&ybf[(size_t)row*HH + k];
  unsigned short* pv = (unsigned short*)&v;
  float o[8];
  for(int j=0;j<8;j++) o[j] = bf2f(pv[j])*scsh[k+j] + scsh[HH+k+j];
  float4* dst = (float4*)&out[((size_t)b*TT + t)*HH + k];
  dst[0] = make_float4(o[0],o[1],o[2],o[3]);
  dst[1] = make_float4(o[4],o[5],o[6],o[7]);
}

__global__ void copy_f32(const float* __restrict__ in, float* __restrict__ out, int n){
  int i = blockIdx.x*blockDim.x + threadIdx.x;
  if(i<n) out[i] = in[i];
}

extern "C" void kernel_launch(void* const* d_in, const int* in_sizes, int n_in,
                              void* d_out, int out_size, void* d_ws, size_t ws_size,
                              hipStream_t stream){
  const int*   x      = (const int*)d_in[0];
  const float* emb    = (const float*)d_in[1];
  const float* k0     = (const float*)d_in[2];
  const float* rk0    = (const float*)d_in[3];
  const float* b0     = (const float*)d_in[4];
  const float* krest  = (const float*)d_in[5];
  const float* rkrest = (const float*)d_in[6];
  const float* brest  = (const float*)d_in[7];
  const float* gammas = (const float*)d_in[8];
  const float* betas  = (const float*)d_in[9];
  float* out_y = (float*)d_out;
  float* out_state = out_y + (size_t)MM*HH;

  char* p = (char*)d_ws;
  auto alloc = [&](size_t bytes)->void*{ void* r = p; p += (bytes + 255) & ~(size_t)255; return r; };
  unsigned short* ybf  = (unsigned short*)alloc((size_t)MM*HH*2);   // [T][B][H]
  unsigned short* y0bf = (unsigned short*)alloc((size_t)MM*EE*2);   // [T][B][E]
  unsigned short* kT0  = (unsigned short*)alloc((size_t)H3*EE*2);
  unsigned short* kT1  = (unsigned short*)alloc((size_t)H3*HH*2);
  unsigned short* kT2  = (unsigned short*)alloc((size_t)H3*HH*2);
  unsigned short* rkT0 = (unsigned short*)alloc((size_t)H3*HH*2);
  unsigned short* rkT1 = (unsigned short*)alloc((size_t)H3*HH*2);
  unsigned short* rkT2 = (unsigned short*)alloc((size_t)H3*HH*2);
  unsigned short* kTs  = (unsigned short*)alloc((size_t)H3*HH*2);
  float* badj   = (float*)alloc(H3*4);
  float* scsh   = (float*)alloc(2*HH*4);
  float* stats  = (float*)alloc(2*2*HH*4);   // [bg][2][512]
  float* hstate = (float*)alloc((size_t)BB*HH*4);
  unsigned short* Hbuf = (unsigned short*)alloc((size_t)2*BB*HH*2);
  int* flags = (int*)alloc(NWG*16*4);   // one cache line per WG
  size_t fixed_bytes = (size_t)(p - (char*)d_ws);

  int C = 64;
  const int cands[4] = {1024, 512, 256, 128};
  for(int i=0;i<4;i++){
    if(fixed_bytes + (size_t)cands[i]*BB*H3*4 <= ws_size){ C = cands[i]; break; }
  }
  float* xproj = (float*)alloc((size_t)C*BB*H3*4);   // [C][B][3H]
  const int NC = TT / C;

  hipMemsetAsync(flags, 0, NWG*16*4, stream);
  hipMemsetAsync(hstate, 0, (size_t)BB*HH*4, stream);

  conv_transpose<<<dim3(EE/32, H3/32), 256, 0, stream>>>(k0, kT0, EE, H3);
  conv_transpose<<<dim3(HH/32, H3/32), 256, 0, stream>>>(krest, kT1, HH, H3);
  conv_transpose<<<dim3(HH/32, H3/32), 256, 0, stream>>>(krest + (size_t)HH*H3, kT2, HH, H3);
  conv_transpose<<<dim3(HH/32, H3/32), 256, 0, stream>>>(rk0, rkT0, HH, H3);
  conv_transpose<<<dim3(HH/32, H3/32), 256, 0, stream>>>(rkrest, rkT1, HH, H3);
  conv_transpose<<<dim3(HH/32, H3/32), 256, 0, stream>>>(rkrest + (size_t)HH*H3, rkT2, HH, H3);
  gather_emb<<<(MM*EE/4 + 255)/256, 256, 0, stream>>>(x, emb, y0bf);

  for(int L=0; L<3; L++){
    hipMemsetAsync(stats, 0, 2*2*HH*4, stream);
    const unsigned short* A; const unsigned short* BT; const float* bias;
    const unsigned short* rk; const float* rbias; int Kd;
    if(L == 0){
      A = y0bf; BT = kT0; bias = b0; rk = rkT0; rbias = b0 + H3; Kd = EE;
    } else {
      const unsigned short* kTn = (L==1) ? kT1 : kT2;
      const float* bn_bias = (L==1) ? brest : brest + 2*H3;
      kscale<<<H3/4, 256, 0, stream>>>(kTn, scsh, bn_bias, kTs, badj);
      A = ybf; BT = kTs; bias = badj; Kd = HH;
      rk = (L==1) ? rkT1 : rkT2;
      rbias = (L==1) ? brest + H3 : brest + 3*H3;
    }
    for(int c=0;c<NC;c++){
      int t0 = c*C;
      gemm_bias<<<dim3(C*BB/64, H3/64), 256, 0, stream>>>(
          A + (size_t)t0*BB*Kd, BT, bias, xproj, C*BB, H3, Kd);
      gru_scan<<<NWG, 256, 0, stream>>>(
          xproj, rk, rbias, hstate, ybf + (size_t)t0*BB*HH,
          stats, Hbuf, flags, C, L*(TT+1) + t0);
    }
    bn_prep<<<2, 256, 0, stream>>>(stats, gammas + L*HH, betas + L*HH, scsh);
  }
  final_out<<<MM/4, 256, 0, stream>>>(ybf, scsh, out_y);
  copy_f32<<<64, 256, 0, stream>>>(hstate, out_state, BB*HH);
}